// Round 1
// baseline (604.599 us; speedup 1.0000x reference)
//
#include <hip/hip_runtime.h>
#include <math.h>

#define D 256
#define NCODE 1024
#define V_TOTAL 65536
#define EPSF 1e-12f

// ---------------- ws layout (in floats) ----------------
// cb_n   : 0         .. 262144   (1024 x 256, normalized codebook, row-major)
// cb_t   : 262144    .. 524288   (256 x 1024, normalized codebook, transposed [k][n])
// idx_ws : 524288    .. 589824   (65536 int32 winning indices)
// counts : 589824    .. 590848   (1024 u32 histogram)
// loss   : 590848               (1 f32 accumulator)

// ---------------- out layout (floats) ----------------
// 0                 : loss
// 1        .. +16777216 : quantized_st
// 16777217          : perplexity
// 16777218 .. +262144   : codebook_weight passthrough
// 17039362 .. +65536    : code_indices (as float values)

__global__ __launch_bounds__(256) void normalize_cb(const float* __restrict__ w,
                                                    float* __restrict__ cb_n,
                                                    float* __restrict__ cb_t) {
    const int wave = threadIdx.x >> 6;
    const int lane = threadIdx.x & 63;
    const int row  = blockIdx.x * 4 + wave;      // 256 blocks * 4 waves = 1024 rows
    float4 wv = *(const float4*)(w + (size_t)row * D + lane * 4);
    float s = wv.x * wv.x + wv.y * wv.y + wv.z * wv.z + wv.w * wv.w;
    #pragma unroll
    for (int off = 32; off; off >>= 1) s += __shfl_xor(s, off);
    const float scale = 1.0f / fmaxf(sqrtf(s), EPSF);
    float4 o;
    o.x = wv.x * scale; o.y = wv.y * scale; o.z = wv.z * scale; o.w = wv.w * scale;
    *(float4*)(cb_n + (size_t)row * D + lane * 4) = o;
    const int k = lane * 4;
    cb_t[(size_t)(k + 0) * NCODE + row] = o.x;
    cb_t[(size_t)(k + 1) * NCODE + row] = o.y;
    cb_t[(size_t)(k + 2) * NCODE + row] = o.z;
    cb_t[(size_t)(k + 3) * NCODE + row] = o.w;
}

// Main kernel: block handles 64 vectors; streams 1024 codes in 8 chunks of 128.
// 256 threads = 16 tm-groups (4 rows each) x 16 tn-groups (8 cols each).
__global__ __launch_bounds__(256) void vq_main(const float* __restrict__ x,
                                               const float* __restrict__ cb_t,
                                               int* __restrict__ idx_ws,
                                               unsigned int* __restrict__ counts,
                                               float* __restrict__ loss_acc,
                                               float* __restrict__ out_idx_f) {
    __shared__ float xl[64 * 260];     // 64 rows, 260-float padded stride (16B-aligned rows)
    __shared__ float nrm_s[64];
    const int tid = threadIdx.x;
    const int v0  = blockIdx.x * 64;

    // ---- stage x tile (coalesced float4 reads, b128 LDS writes) ----
    const float4* xg = (const float4*)(x + (size_t)v0 * D);
    #pragma unroll
    for (int i = 0; i < 16; ++i) {
        const int f  = tid + i * 256;       // float4 index in tile, 0..4095
        const int m  = f >> 6;              // 64 float4 per row
        const int kk = (f & 63) << 2;
        float4 val = xg[f];
        *(float4*)&xl[m * 260 + kk] = val;
    }
    __syncthreads();

    // ---- per-row norms from LDS (4 threads per row) ----
    {
        const int row = tid >> 2, part = tid & 3;
        float ss = 0.f;
        #pragma unroll
        for (int q = 0; q < 16; ++q) {
            float4 xv = *(const float4*)&xl[row * 260 + part * 64 + q * 4];
            ss += xv.x * xv.x + xv.y * xv.y + xv.z * xv.z + xv.w * xv.w;
        }
        ss += __shfl_xor(ss, 1);
        ss += __shfl_xor(ss, 2);
        if (part == 0) nrm_s[row] = fmaxf(sqrtf(ss), EPSF);
    }
    __syncthreads();

    const int tn = tid & 15, tm = tid >> 4;
    float best[4]; int bidx[4];
    #pragma unroll
    for (int i = 0; i < 4; ++i) { best[i] = -3.4e38f; bidx[i] = 0; }

    const float* bp = cb_t + tn * 8;

    #pragma unroll 1
    for (int c = 0; c < 8; ++c) {
        const int n0 = c * 128 + tn * 8;
        const float* bc = bp + c * 128;
        float acc[4][8];
        #pragma unroll
        for (int i = 0; i < 4; ++i)
            #pragma unroll
            for (int j = 0; j < 8; ++j) acc[i][j] = 0.f;

        #pragma unroll 2
        for (int k4 = 0; k4 < 64; ++k4) {
            float4 xa[4];
            #pragma unroll
            for (int i = 0; i < 4; ++i)
                xa[i] = *(const float4*)&xl[(tm * 4 + i) * 260 + k4 * 4];
            #pragma unroll
            for (int kk = 0; kk < 4; ++kk) {
                const float* bk = bc + (size_t)(k4 * 4 + kk) * NCODE;
                float4 b0 = *(const float4*)bk;
                float4 b1 = *(const float4*)(bk + 4);
                #pragma unroll
                for (int i = 0; i < 4; ++i) {
                    const float xv = ((const float*)&xa[i])[kk];
                    acc[i][0] = fmaf(xv, b0.x, acc[i][0]);
                    acc[i][1] = fmaf(xv, b0.y, acc[i][1]);
                    acc[i][2] = fmaf(xv, b0.z, acc[i][2]);
                    acc[i][3] = fmaf(xv, b0.w, acc[i][3]);
                    acc[i][4] = fmaf(xv, b1.x, acc[i][4]);
                    acc[i][5] = fmaf(xv, b1.y, acc[i][5]);
                    acc[i][6] = fmaf(xv, b1.z, acc[i][6]);
                    acc[i][7] = fmaf(xv, b1.w, acc[i][7]);
                }
            }
        }
        // running argmax (ascending n per thread; strict > keeps lowest index on ties)
        #pragma unroll
        for (int i = 0; i < 4; ++i)
            #pragma unroll
            for (int j = 0; j < 8; ++j) {
                if (acc[i][j] > best[i]) { best[i] = acc[i][j]; bidx[i] = n0 + j; }
            }
    }

    // ---- argmax reduce across the 16 tn lanes (low 4 bits of lane id) ----
    #pragma unroll
    for (int off = 8; off; off >>= 1) {
        #pragma unroll
        for (int i = 0; i < 4; ++i) {
            float ov = __shfl_xor(best[i], off);
            int   oi = __shfl_xor(bidx[i], off);
            if (ov > best[i] || (ov == best[i] && oi < bidx[i])) { best[i] = ov; bidx[i] = oi; }
        }
    }

    // ---- epilogue ----
    float lpart = 0.f;
    if (tn == 0) {
        #pragma unroll
        for (int i = 0; i < 4; ++i) {
            const int row = tm * 4 + i;
            const int v   = v0 + row;
            const float sim = best[i] / nrm_s[row];
            lpart += 2.f - 2.f * sim;
            idx_ws[v] = bidx[i];
            out_idx_f[v] = (float)bidx[i];
            atomicAdd(&counts[bidx[i]], 1u);
        }
    }
    #pragma unroll
    for (int off = 32; off; off >>= 1) lpart += __shfl_xor(lpart, off);
    if ((tid & 63) == 0) atomicAdd(loss_acc, lpart);
}

__global__ __launch_bounds__(256) void gather_q(const int* __restrict__ idx_ws,
                                                const float* __restrict__ cb_n,
                                                float* __restrict__ outq) {
    const int wave = threadIdx.x >> 6;
    const int lane = threadIdx.x & 63;
    const int v = blockIdx.x * 4 + wave;
    const int idx = idx_ws[v];
    float4 val = *(const float4*)(cb_n + (size_t)idx * D + lane * 4);
    *(float4*)(outq + (size_t)v * D + lane * 4) = val;
}

__global__ __launch_bounds__(1024) void finalize(const unsigned int* __restrict__ counts,
                                                 const float* __restrict__ loss_acc,
                                                 float* __restrict__ out_loss,
                                                 float* __restrict__ out_perp) {
    __shared__ float red[16];
    const int t = threadIdx.x;
    const float p = (float)counts[t] / 65536.0f;
    float term = p * logf(p + 1e-10f);
    #pragma unroll
    for (int off = 32; off; off >>= 1) term += __shfl_xor(term, off);
    if ((t & 63) == 0) red[t >> 6] = term;
    __syncthreads();
    if (t < 16) {
        float s = red[t];
        #pragma unroll
        for (int off = 8; off; off >>= 1) s += __shfl_xor(s, off);
        if (t == 0) {
            *out_perp = expf(-s);
            *out_loss = 1.25f * (*loss_acc) / 16777216.0f;
        }
    }
}

extern "C" void kernel_launch(void* const* d_in, const int* in_sizes, int n_in,
                              void* d_out, int out_size, void* d_ws, size_t ws_size,
                              hipStream_t stream) {
    const float* x  = (const float*)d_in[0];
    const float* cw = (const float*)d_in[1];
    float* out = (float*)d_out;
    float* ws  = (float*)d_ws;

    float* cb_n          = ws;
    float* cb_t          = ws + 262144;
    int* idx_ws          = (int*)(ws + 524288);
    unsigned int* counts = (unsigned int*)(ws + 589824);
    float* loss_acc      = ws + 590848;

    // zero histogram + loss accumulator (contiguous region)
    hipMemsetAsync(counts, 0, (1024 + 1) * sizeof(float), stream);

    normalize_cb<<<256, 256, 0, stream>>>(cw, cb_n, cb_t);
    vq_main<<<1024, 256, 0, stream>>>(x, cb_t, idx_ws, counts, loss_acc,
                                      out + 17039362);
    gather_q<<<16384, 256, 0, stream>>>(idx_ws, cb_n, out + 1);
    finalize<<<1, 1024, 0, stream>>>(counts, loss_acc, out, out + 16777217);
    hipMemcpyAsync(out + 16777218, cw, (size_t)NCODE * D * sizeof(float),
                   hipMemcpyDeviceToDevice, stream);
}